// Round 4
// baseline (323.834 us; speedup 1.0000x reference)
//
#include <hip/hip_runtime.h>

// Adaptive db4 wavelet transform, 5-level cascade, per-feature level select.
// B=32, S=4096, F=64, layout (b,s,f) f-contiguous. float4 across f.
// Cascade lengths 2048/1024/512/256/128; lo_j[n] = sum_i h0[i]*lo_{j-1}[2n+i-3],
// hi_j[n] likewise with h1 (zero outside [0,Tin)).
//
// Structure: 4 small pyramid kernels build lo1..lo4 in d_ws (work-sized grids),
// then ONE output kernel computes det1..5 / high_freq / approx / low_freq all in
// registers (det_j and lo_j share the same 8-tap window over lo_{j-1}; approx is
// the thread's own lo_{lv} value; hf is the running sum of masked dets) and does
// 8 coalesced float4 stores per thread.
//
// Output concat: approx[BSF] | det1..det5[5*BSF] | high_freq[BSF] | low_freq[BSF]

#define NB 32
#define NS 4096
#define NF 64
#define BSF (NB * NS * NF)
#define NF4 (NF / 4)

__constant__ float c_h0[8] = {
     0.23037781330885523f,  0.7148465705525415f,   0.6308807679295904f,
    -0.02798376941698385f, -0.18703481171888114f,  0.030841381835986965f,
     0.032883011666982945f, -0.010597401784997278f};
__constant__ float c_h1[8] = {
    -0.010597401784997278f, -0.032883011666982945f, 0.030841381835986965f,
     0.18703481171888114f,  -0.02798376941698385f,  -0.6308807679295904f,
     0.7148465705525415f,   -0.23037781330885523f};

__device__ __forceinline__ int get_level(const float* __restrict__ scores, int f) {
    int lv = 2 + (int)rintf(scores[f] * 3.0f);   // round-half-even, matches jnp
    return min(5, max(2, lv));
}

// 8-tap analysis window at output index n over src (TIN rows, float4 lanes).
template <int TIN>
__device__ __forceinline__ void conv8(const float4* __restrict__ src, int b, int n,
                                      int f4, float4& lo, float4& hi) {
    lo = {0.f, 0.f, 0.f, 0.f};
    hi = {0.f, 0.f, 0.f, 0.f};
    int base = 2 * n - 3;
    const float4* row = src + (size_t)b * TIN * NF4 + f4;
#pragma unroll
    for (int i = 0; i < 8; ++i) {
        int m = base + i;
        if ((unsigned)m < (unsigned)TIN) {
            float4 v = row[(size_t)m * NF4];
            lo.x = fmaf(c_h0[i], v.x, lo.x);  hi.x = fmaf(c_h1[i], v.x, hi.x);
            lo.y = fmaf(c_h0[i], v.y, lo.y);  hi.y = fmaf(c_h1[i], v.y, hi.y);
            lo.z = fmaf(c_h0[i], v.z, lo.z);  hi.z = fmaf(c_h1[i], v.z, hi.z);
            lo.w = fmaf(c_h0[i], v.w, lo.w);  hi.w = fmaf(c_h1[i], v.w, hi.w);
        }
    }
}

// Pyramid kernel: lo_{j-1} (TIN rows) -> lo_j (LEN = TIN/2 rows). Work-sized grid.
template <int TIN, int LOG2LEN>
__global__ __launch_bounds__(256) void wl_lo(
    const float4* __restrict__ in, float4* __restrict__ lo_out)
{
    constexpr int LEN = 1 << LOG2LEN;
    int t = blockIdx.x * 256 + threadIdx.x;    // grid covers NB*LEN*NF4 exactly
    int f4 = t & (NF4 - 1);
    int r = t >> 4;
    int n = r & (LEN - 1);
    int b = r >> LOG2LEN;

    float4 lo, hi;
    conv8<TIN>(in, b, n, f4, lo, hi);
    lo_out[(size_t)(b * LEN + n) * NF4 + f4] = lo;
}

// Output kernel: everything else. One thread per (b, n, f4).
__global__ __launch_bounds__(256) void wl_out(
    const float4* __restrict__ x,
    const float4* __restrict__ lo1, const float4* __restrict__ lo2,
    const float4* __restrict__ lo3, const float4* __restrict__ lo4,
    float* __restrict__ out, const float* __restrict__ scores)
{
    int t = blockIdx.x * 256 + threadIdx.x;    // grid covers BSF/4
    int f4 = t & (NF4 - 1);
    int r = t >> 4;
    int n = r & (NS - 1);
    int b = r >> 12;
    int f0 = f4 * 4;

    int lv[4];
#pragma unroll
    for (int c = 0; c < 4; ++c) lv[c] = get_level(scores, f0 + c);

    const float4 z = {0.f, 0.f, 0.f, 0.f};
    float4 d1 = z, d2 = z, d3 = z, d4 = z, d5 = z;
    float4 l1 = z, l2 = z, l3 = z, l4 = z, l5 = z;

    if (n < 2048) conv8<4096>(x,   b, n, f4, l1, d1);
    if (n < 1024) conv8<2048>(lo1, b, n, f4, l2, d2);
    if (n < 512)  conv8<1024>(lo2, b, n, f4, l3, d3);
    if (n < 256)  conv8<512> (lo3, b, n, f4, l4, d4);
    if (n < 128)  conv8<256> (lo4, b, n, f4, l5, d5);

    // mask details for j >= 3 (lv >= 2 always, so d1/d2 unmasked)
    if (lv[0] < 3) d3.x = 0.f;  if (lv[0] < 4) d4.x = 0.f;  if (lv[0] < 5) d5.x = 0.f;
    if (lv[1] < 3) d3.y = 0.f;  if (lv[1] < 4) d4.y = 0.f;  if (lv[1] < 5) d5.y = 0.f;
    if (lv[2] < 3) d3.z = 0.f;  if (lv[2] < 4) d4.z = 0.f;  if (lv[2] < 5) d5.z = 0.f;
    if (lv[3] < 3) d3.w = 0.f;  if (lv[3] < 4) d4.w = 0.f;  if (lv[3] < 5) d5.w = 0.f;

    float4 hf;
    hf.x = d1.x + d2.x + d3.x + d4.x + d5.x;
    hf.y = d1.y + d2.y + d3.y + d4.y + d5.y;
    hf.z = d1.z + d2.z + d3.z + d4.z + d5.z;
    hf.w = d1.w + d2.w + d3.w + d4.w + d5.w;

    // approx = lo_{lv}[n] (already zero past each level's length)
    float4 av;
    av.x = (lv[0] == 2) ? l2.x : (lv[0] == 3) ? l3.x : (lv[0] == 4) ? l4.x : l5.x;
    av.y = (lv[1] == 2) ? l2.y : (lv[1] == 3) ? l3.y : (lv[1] == 4) ? l4.y : l5.y;
    av.z = (lv[2] == 2) ? l2.z : (lv[2] == 3) ? l3.z : (lv[2] == 4) ? l4.z : l5.z;
    av.w = (lv[3] == 2) ? l2.w : (lv[3] == 3) ? l3.w : (lv[3] == 4) ? l4.w : l5.w;

    float4* o = (float4*)out;
    o[(size_t)0 * BSF / 4 + t] = av;   // approx
    o[(size_t)1 * BSF / 4 + t] = d1;
    o[(size_t)2 * BSF / 4 + t] = d2;
    o[(size_t)3 * BSF / 4 + t] = d3;
    o[(size_t)4 * BSF / 4 + t] = d4;
    o[(size_t)5 * BSF / 4 + t] = d5;
    o[(size_t)6 * BSF / 4 + t] = hf;   // high_freq
    o[(size_t)7 * BSF / 4 + t] = av;   // low_freq
}

extern "C" void kernel_launch(void* const* d_in, const int* in_sizes, int n_in,
                              void* d_out, int out_size, void* d_ws, size_t ws_size,
                              hipStream_t stream)
{
    const float4* x     = (const float4*)d_in[0];
    const float* scores = (const float*)d_in[1];
    float* out = (float*)d_out;
    float* ws  = (float*)d_ws;

    // lo pyramid in workspace: 2048+1024+512+256 rows of NB*NF floats = 30 MiB
    float4* lo1 = (float4*)ws;
    float4* lo2 = lo1 + (size_t)NB * 2048 * NF4;
    float4* lo3 = lo2 + (size_t)NB * 1024 * NF4;
    float4* lo4 = lo3 + (size_t)NB * 512 * NF4;

    dim3 block(256);
    wl_lo<4096, 11><<<dim3(NB * 2048 * NF4 / 256), block, 0, stream>>>(x,   lo1);
    wl_lo<2048, 10><<<dim3(NB * 1024 * NF4 / 256), block, 0, stream>>>(lo1, lo2);
    wl_lo<1024,  9><<<dim3(NB *  512 * NF4 / 256), block, 0, stream>>>(lo2, lo3);
    wl_lo< 512,  8><<<dim3(NB *  256 * NF4 / 256), block, 0, stream>>>(lo3, lo4);
    wl_out<<<dim3(BSF / 4 / 256), block, 0, stream>>>(x, lo1, lo2, lo3, lo4, out, scores);
}

// Round 5
// 308.129 us; speedup vs baseline: 1.0510x; 1.0510x over previous
//
#include <hip/hip_runtime.h>

// Adaptive db4 wavelet transform, 5-level cascade, per-feature level select.
// B=32, S=4096, F=64, (b,s,f) f-contiguous. 16B vector lanes across f.
// lo_j[n] = sum_i h0[i]*lo_{j-1}[2n+i-3] (zero outside [0,Tin)), lengths
// 2048/1024/512/256/128.
//
// K1..K4: work-sized grids, each thread computes an n-PAIR (10 tap loads for
// 2 outputs), writes lo_j head (ws) + det_j head (out). K5 (full grid): level-5
// conv, high_freq sum (reads det heads, LLC-warm), approx/low_freq gather,
// and ALL det zero tails — streaming nontemporal stores for never-re-read data.
//
// Output concat: approx[BSF] | det1..det5[5*BSF] | high_freq[BSF] | low_freq[BSF]

#define NB 32
#define NS 4096
#define NF 64
#define BSF (NB * NS * NF)
#define NF4 (NF / 4)

typedef float f4v __attribute__((ext_vector_type(4)));

__constant__ float c_h0[8] = {
     0.23037781330885523f,  0.7148465705525415f,   0.6308807679295904f,
    -0.02798376941698385f, -0.18703481171888114f,  0.030841381835986965f,
     0.032883011666982945f, -0.010597401784997278f};
__constant__ float c_h1[8] = {
    -0.010597401784997278f, -0.032883011666982945f, 0.030841381835986965f,
     0.18703481171888114f,  -0.02798376941698385f,  -0.6308807679295904f,
     0.7148465705525415f,   -0.23037781330885523f};

__device__ __forceinline__ int get_level(const float* __restrict__ scores, int f) {
    int lv = 2 + (int)rintf(scores[f] * 3.0f);   // round-half-even, matches jnp
    return min(5, max(2, lv));
}

// Level kernel: in (TIN rows) -> lo head (LEN rows, ws) + det_J head (out, NS stride).
// Each thread owns the n-pair (2np, 2np+1): 10 tap rows cover both 8-tap windows.
template <int J, int TIN, int LOG2LEN>
__global__ __launch_bounds__(256) void wl_lvl(
    const f4v* __restrict__ in, f4v* __restrict__ lo_out,
    f4v* __restrict__ det, const float* __restrict__ scores)
{
    constexpr int LEN = 1 << LOG2LEN;
    int t = blockIdx.x * 256 + threadIdx.x;       // grid = NB*(LEN/2)*NF4 threads
    int f4 = t & (NF4 - 1);
    int r = t >> 4;
    int np = r & (LEN / 2 - 1);
    int b = r >> (LOG2LEN - 1);
    int n0 = 2 * np;

    const f4v* row = in + (size_t)b * TIN * NF4 + f4;
    const f4v z = {0.f, 0.f, 0.f, 0.f};
    f4v v[10];
    int base = n0 * 2 - 3;
#pragma unroll
    for (int j = 0; j < 10; ++j) {
        int m = base + j;
        v[j] = ((unsigned)m < (unsigned)TIN) ? row[(size_t)m * NF4] : z;
    }
    f4v lo0 = z, hi0 = z, lo1 = z, hi1 = z;
#pragma unroll
    for (int i = 0; i < 8; ++i) {
        lo0 += c_h0[i] * v[i];      hi0 += c_h1[i] * v[i];
        lo1 += c_h0[i] * v[i + 2];  hi1 += c_h1[i] * v[i + 2];
    }
    if (J >= 3) {                                  // det_J kept iff lv[f] >= J
        int f0 = f4 * 4;
#pragma unroll
        for (int c = 0; c < 4; ++c)
            if (get_level(scores, f0 + c) < J) { hi0[c] = 0.f; hi1[c] = 0.f; }
    }
    f4v* lp = lo_out + (size_t)(b * LEN + n0) * NF4 + f4;
    lp[0] = lo0;  lp[NF4] = lo1;
    f4v* dp = det + (size_t)(b * NS + n0) * NF4 + f4;
    dp[0] = hi0;  dp[NF4] = hi1;
}

// Final kernel (full grid): level-5 conv + det5, high_freq, approx/low_freq,
// det1..det4 zero tails. Nontemporal stores for everything never re-read.
__global__ __launch_bounds__(256) void wl_final(
    const float* __restrict__ lo2s, const float* __restrict__ lo3s,
    const float* __restrict__ lo4s, f4v* __restrict__ out4,
    const float* __restrict__ scores)
{
    int t = blockIdx.x * 256 + threadIdx.x;        // grid = BSF/4 threads
    int f4 = t & (NF4 - 1);
    int r = t >> 4;
    int n = r & (NS - 1);
    int b = r >> 12;
    int f0 = f4 * 4;

    int lv[4];
#pragma unroll
    for (int c = 0; c < 4; ++c) lv[c] = get_level(scores, f0 + c);

    const f4v z = {0.f, 0.f, 0.f, 0.f};
    f4v d5 = z, l5 = z;
    if (n < 128) {                                 // level-5 conv over lo4 (256 rows)
        const f4v* row = (const f4v*)lo4s + (size_t)b * 256 * NF4 + f4;
        int base = 2 * n - 3;
        f4v hi = z;
#pragma unroll
        for (int i = 0; i < 8; ++i) {
            int m = base + i;
            if ((unsigned)m < 256u) {
                f4v v = row[(size_t)m * NF4];
                l5 += c_h0[i] * v;  hi += c_h1[i] * v;
            }
        }
#pragma unroll
        for (int c = 0; c < 4; ++c) d5[c] = (lv[c] >= 5) ? hi[c] : 0.f;
    }

    f4v* det1 = out4 + (size_t)1 * (BSF / 4);
    f4v* det2 = out4 + (size_t)2 * (BSF / 4);
    f4v* det3 = out4 + (size_t)3 * (BSF / 4);
    f4v* det4 = out4 + (size_t)4 * (BSF / 4);

    // high_freq = sum of masked details (heads written by K1..K4; det5 in regs)
    f4v acc = d5;
    if (n < 2048) {
        acc += det1[t];
        if (n < 1024) acc += det2[t];
        if (n < 512)  acc += det3[t];
        if (n < 256)  acc += det4[t];
    }

    // approx / low_freq: component c = lowpass after lv[c] levels, zero tail
    f4v av = z;
#pragma unroll
    for (int c = 0; c < 4; ++c) {
        int L = lv[c];
        int len = 2048 >> (L - 1);                 // 1024/512/256/128 for L=2..5
        float vv = 0.f;
        if (n < len) {
            if (L == 5)      vv = l5[c];
            else if (L == 4) vv = lo4s[(size_t)(b * 256 + n) * NF + f0 + c];
            else if (L == 3) vv = lo3s[(size_t)(b * 512 + n) * NF + f0 + c];
            else             vv = lo2s[(size_t)(b * 1024 + n) * NF + f0 + c];
        }
        av[c] = vv;
    }

    __builtin_nontemporal_store(av,  out4 + t);                        // approx
    __builtin_nontemporal_store(d5,  out4 + (size_t)5 * (BSF / 4) + t); // det5
    __builtin_nontemporal_store(acc, out4 + (size_t)6 * (BSF / 4) + t); // high_freq
    __builtin_nontemporal_store(av,  out4 + (size_t)7 * (BSF / 4) + t); // low_freq
    if (n >= 2048) __builtin_nontemporal_store(z, det1 + t);           // zero tails
    if (n >= 1024) __builtin_nontemporal_store(z, det2 + t);
    if (n >= 512)  __builtin_nontemporal_store(z, det3 + t);
    if (n >= 256)  __builtin_nontemporal_store(z, det4 + t);
}

extern "C" void kernel_launch(void* const* d_in, const int* in_sizes, int n_in,
                              void* d_out, int out_size, void* d_ws, size_t ws_size,
                              hipStream_t stream)
{
    const f4v* x        = (const f4v*)d_in[0];
    const float* scores = (const float*)d_in[1];
    f4v* out4 = (f4v*)d_out;
    float* ws = (float*)d_ws;

    // lo pyramid in workspace: (2048+1024+512+256) * NB*NF floats = 30 MiB
    f4v* lo1 = (f4v*)ws;
    f4v* lo2 = lo1 + (size_t)NB * 2048 * NF4;
    f4v* lo3 = lo2 + (size_t)NB * 1024 * NF4;
    f4v* lo4 = lo3 + (size_t)NB * 512 * NF4;

    f4v* det1 = out4 + (size_t)1 * (BSF / 4);
    f4v* det2 = out4 + (size_t)2 * (BSF / 4);
    f4v* det3 = out4 + (size_t)3 * (BSF / 4);
    f4v* det4 = out4 + (size_t)4 * (BSF / 4);

    dim3 block(256);
    wl_lvl<1, 4096, 11><<<dim3(NB * 1024 * NF4 / 256), block, 0, stream>>>(x,   lo1, det1, scores);
    wl_lvl<2, 2048, 10><<<dim3(NB *  512 * NF4 / 256), block, 0, stream>>>(lo1, lo2, det2, scores);
    wl_lvl<3, 1024,  9><<<dim3(NB *  256 * NF4 / 256), block, 0, stream>>>(lo2, lo3, det3, scores);
    wl_lvl<4,  512,  8><<<dim3(NB *  128 * NF4 / 256), block, 0, stream>>>(lo3, lo4, det4, scores);
    wl_final<<<dim3(BSF / 4 / 256), block, 0, stream>>>((const float*)lo2, (const float*)lo3,
                                                        (const float*)lo4, out4, scores);
}